// Round 1
// baseline (39.076 us; speedup 1.0000x reference)
//
#include <hip/hip_runtime.h>
#include <hip/hip_bf16.h>
#include <cstdint>

#define HW 112
#define NPIX (HW*HW)   // 12544
#define NB 2
#define NC 4

// ws layout:
//   [0..23]  float accum (12 sums, 12 counts), zeroed by prep_kernel block 0
//   +256:    packed masks  uint64_t[12 masks][112 rows][2 words]
//   +256+21504: g planes   uint8_t[12 planes][12544]
// mask id = b*6 + m, m=0..2 -> A(j=m+1) (argmax==j), m=3..5 -> B(j=m-2) (label==1)

__global__ __launch_bounds__(128) void prep_kernel(
    const float* __restrict__ pred, const int* __restrict__ labels,
    float* __restrict__ accum, unsigned long long* __restrict__ masks,
    unsigned char* __restrict__ gbuf)
{
  int blk = blockIdx.x;
  int b = blk / HW, r = blk % HW;
  int tid = threadIdx.x;
  int lane = tid & 63, wave = tid >> 6;
  int c = tid;

  if (blk == 0 && tid < 24) accum[tid] = 0.f;

  int cls = 255;
  if (c < HW) {
    const float* p0 = pred + ((size_t)(b*NC)*HW + r)*HW + c;
    float best = p0[0]; cls = 0;
    #pragma unroll
    for (int ch = 1; ch < NC; ch++) {
      float v = p0[(size_t)ch*NPIX];
      if (v > best) { best = v; cls = ch; }   // strict > : first-index tie-break like argmax
    }
  }

  __shared__ unsigned long long sm[6][2];
  #pragma unroll
  for (int m = 0; m < 3; m++) {
    bool p = (c < HW) && (cls == m + 1);
    unsigned long long bal = __ballot(p);
    if (lane == 0) sm[m][wave] = bal;
  }
  #pragma unroll
  for (int m = 0; m < 3; m++) {
    int lab = (c < HW) ? labels[((size_t)(b*NC + (m+1))*HW + r)*HW + c] : 0;
    bool p = (c < HW) && (lab == 1);
    unsigned long long bal = __ballot(p);
    if (lane == 0) sm[3 + m][wave] = bal;
  }
  __syncthreads();

  if (tid < 12) {
    int m = tid >> 1, w = tid & 1;
    masks[((size_t)(b*6 + m)*HW + r)*2 + w] = sm[m][w];
  }

  // phase 1: horizontal nearest-set-pixel distance, O(1)/pixel via clz/ffs
  for (int item = tid; item < 6*HW; item += 128) {
    int m = item / HW, cc = item % HW;
    unsigned long long lo = sm[m][0], hi = sm[m][1];
    int left, right;
    if (cc < 64) {
      unsigned long long wl = lo & ((2ull << cc) - 1);           // bits 0..cc
      left = wl ? 63 - __clzll(wl) : -1000;
      unsigned long long wr = lo & ~((1ull << cc) - 1);          // bits cc..63
      right = wr ? __ffsll(wr) - 1 : (hi ? 64 + __ffsll(hi) - 1 : 1000);
    } else {
      int cl = cc - 64;
      unsigned long long wl = hi & ((2ull << cl) - 1);           // bits 64..cc
      left = wl ? 64 + 63 - __clzll(wl) : (lo ? 63 - __clzll(lo) : -1000);
      unsigned long long wr = hi & ~((1ull << cl) - 1);          // bits cc..111
      right = wr ? 64 + __ffsll(wr) - 1 : 1000;
    }
    int gv = min(cc - left, right - cc);
    gv = min(gv, 255);  // 255 = "row empty" sentinel; 255^2 > max real d^2 = 24642
    gbuf[(size_t)(b*6 + m)*NPIX + r*HW + cc] = (unsigned char)gv;
  }
}

// one block per (pair-dir, row): phase-2 vertical min + masked sum/count reduce
__global__ __launch_bounds__(128) void hd_kernel(
    const unsigned long long* __restrict__ masks,
    const unsigned char* __restrict__ gbuf,
    float* __restrict__ accum)
{
  int blk = blockIdx.x;
  int pd = blk / HW, r = blk % HW;
  int b = pd / 6, k = pd % 6;
  // k<3: fwd for j=k+1 (src plane = B mask, target = A mask)
  // k>=3: rev for j=k-2 (src plane = A mask, target = B mask)
  int src = b*6 + (k + 3) % 6;
  int tgt = b*6 + k;
  int tid = threadIdx.x, lane = tid & 63, wave = tid >> 6, c = tid;

  bool inT = false;
  float val = 0.f;
  if (c < HW) {
    unsigned long long w = masks[((size_t)tgt*HW + r)*2 + (c >> 6)];
    inT = (w >> (c & 63)) & 1ull;
    const unsigned char* gp = gbuf + (size_t)src*NPIX + c;
    int mind = 0x7fffffff;
    #pragma unroll 8
    for (int rp = 0; rp < HW; rp++) {
      int gg = gp[(size_t)rp*HW];
      int dr = r - rp;
      int d = dr*dr + gg*gg;
      mind = min(mind, d);
    }
    val = inT ? sqrtf((float)mind) : 0.f;
  }

  unsigned long long bal = __ballot(inT);
  float s = val;
  #pragma unroll
  for (int off = 32; off; off >>= 1) s += __shfl_down(s, off, 64);
  __shared__ float ssum[2];
  __shared__ int scnt[2];
  if (lane == 0) { ssum[wave] = s; scnt[wave] = __popcll(bal); }
  __syncthreads();
  if (tid == 0) {
    atomicAdd(&accum[pd], ssum[0] + ssum[1]);
    atomicAdd(&accum[12 + pd], (float)(scnt[0] + scnt[1]));
  }
}

__global__ void fin_kernel(const float* __restrict__ accum, float* __restrict__ out)
{
  if (threadIdx.x == 0) {
    float mhd[6], fhd[6], rhd[6];
    for (int i = 0; i < 6; i++) { mhd[i] = 0.f; fhd[i] = 0.f; rhd[i] = 0.f; }
    for (int b = 0; b < 2; b++)
      for (int j = 1; j < 4; j++) {
        int pf = b*6 + (j - 1);
        int pr = b*6 + 3 + (j - 1);
        float fwd = accum[pf] / accum[12 + pf];
        float rev = accum[pr] / accum[12 + pr];
        fhd[j] += fwd; rhd[j] += rev; mhd[j] += fmaxf(fwd, rev);
      }
    float* arrs[3] = { mhd, fhd, rhd };
    for (int a = 0; a < 3; a++) {
      float* x = arrs[a];
      for (int i = 0; i < 4; i++) x[i] *= 0.5f;          // /N
      x[4] = (x[0] + x[1] + x[2] + x[3]) * 0.25f;        // mean(x[:C])
      x[5] = (x[1] + x[2] + x[3]) * (1.f / 3.f);         // mean(x[1:C])
      for (int i = 0; i < 6; i++) out[a*6 + i] = x[i];
    }
  }
}

extern "C" void kernel_launch(void* const* d_in, const int* in_sizes, int n_in,
                              void* d_out, int out_size, void* d_ws, size_t ws_size,
                              hipStream_t stream) {
  const float* pred = (const float*)d_in[0];
  const int* labels = (const int*)d_in[1];
  float* out = (float*)d_out;

  float* accum = (float*)d_ws;
  unsigned long long* masks = (unsigned long long*)((char*)d_ws + 256);
  unsigned char* gbuf = (unsigned char*)((char*)d_ws + 256 + (size_t)12*HW*2*sizeof(unsigned long long));

  prep_kernel<<<NB*HW, 128, 0, stream>>>(pred, labels, accum, masks, gbuf);
  hd_kernel<<<12*HW, 128, 0, stream>>>(masks, gbuf, accum);
  fin_kernel<<<1, 64, 0, stream>>>(accum, out);
}